// Round 1
// baseline (419.547 us; speedup 1.0000x reference)
//
#include <hip/hip_runtime.h>

// SNN: 3-layer LIF, B=256, T=32, H=1024, IN=2312, OUT=10.
// GEMMs on MFMA (bf16) via exact 3-way bf16 split of fp32 operands
// (pairs pa+pb<=2 => fp32-equivalent; round-2 absmax was 0.0).
// Round-3: LDS row pad 36, A-fragment dedup.
// Round-4: 512-thread / 8-wave blocks (same 128x128 tile, per-wave 32x64).
//   LDS unchanged (55296B -> 2 blocks/CU) but waves/CU 8 -> 16 (occupancy
//   21.5% -> ~45%): the per-tile commit+barrier serial section was leaving
//   the MFMA pipe idle (MfmaUtil 42%, VALU 25%, 33% stall) with only
//   2 waves/SIMD. acc 64->32 VGPR, afr 48->24 keeps us under the 128-VGPR
//   budget 16 waves/CU needs.

#define TB 256
#define TT 32
#define TH 1024
#define TIN 2312
#define TOUT 10
#define TM (TT * TB)   // 8192 rows = (t,b)
#define KP1 2368       // TIN padded to multiple of 32

typedef __bf16 bf16_t;
typedef bf16_t bf16x8 __attribute__((ext_vector_type(8)));
typedef bf16_t bf16x4 __attribute__((ext_vector_type(4)));
typedef float floatx4 __attribute__((ext_vector_type(4)));

__device__ __forceinline__ void split3(float v, bf16_t& a, bf16_t& b, bf16_t& c) {
  a = (bf16_t)v;
  float r1 = v - (float)a;
  b = (bf16_t)r1;
  c = (bf16_t)(r1 - (float)b);
}

// W (rows x K) -> 3 bf16 planes (rows x Kp), zero-padded K..Kp.
__global__ __launch_bounds__(256) void split_w(const float* __restrict__ W,
                                               bf16_t* __restrict__ P,
                                               long plane, int K, int Kp) {
  int k4 = (blockIdx.x * 256 + threadIdx.x) * 4;
  if (k4 >= Kp) return;
  long r = blockIdx.y;
  float4 v = (k4 < K) ? *(const float4*)(W + r * (long)K + k4)
                      : float4{0.f, 0.f, 0.f, 0.f};
  float t[4] = {v.x, v.y, v.z, v.w};
  bf16x4 a, b, c;
  #pragma unroll
  for (int e = 0; e < 4; ++e) {
    bf16_t x, y, z;
    split3(t[e], x, y, z);
    a[e] = x; b[e] = y; c[e] = z;
  }
  long o = r * (long)Kp + k4;
  *(bf16x4*)(P + o) = a;
  *(bf16x4*)(P + plane + o) = b;
  *(bf16x4*)(P + 2 * plane + o) = c;
}

// C[r][n] = sum_pairs sum_k Apa[r][k]*Bpb[n][k] + bias[n]
// A row element offset = (r>>8)*sT + (r&255)*sB.
// 512 threads = 8 waves laid out 4(M) x 2(N); per-wave 32x64 output.
template <bool AF32>
__global__ __launch_bounds__(512, 4) void snn_gemm(
    const float* __restrict__ Af, const bf16_t* __restrict__ Ab,
    long sT, long sB, const bf16_t* __restrict__ Bp, long planeB,
    int Kp, int K, const float* __restrict__ bias,
    float* __restrict__ C, int N) {
  constexpr int APL = AF32 ? 3 : 1;
  constexpr int LDW = 36;  // 32 + 4 pad: row*18 mod 32 covers all even bank
                           // bases -> fragment reads ~2-way (free, m136)
  __shared__ bf16_t As[APL][128 * LDW];
  __shared__ bf16_t Bs[3][128 * LDW];

  const int tid = threadIdx.x;
  const int wave = tid >> 6, lane = tid & 63;
  const int quad = lane >> 4, l16 = lane & 15;
  const int wm = (wave & 3) * 32, wn = (wave >> 2) * 64;
  const long m0 = (long)blockIdx.x * 128, n0 = (long)blockIdx.y * 128;

  floatx4 acc[2][4];
  #pragma unroll
  for (int i = 0; i < 2; ++i)
    #pragma unroll
    for (int j = 0; j < 4; ++j) acc[i][j] = (floatx4){0.f, 0.f, 0.f, 0.f};

  // staging registers: each thread owns one (row, 8-elem K-seg) slot
  const int cr = tid >> 2;        // tile row 0..127
  const int cs = (tid & 3) * 8;   // K-seg elem offset 0/8/16/24
  float4 xv[2];
  bf16x8 av;
  bf16x8 bv[3];

  auto prefetch = [&](int kb) {
    const long rA = m0 + cr;
    const int k0 = kb + cs;
    if constexpr (AF32) {
      const float* xr = Af + (rA >> 8) * sT + (rA & 255) * sB + k0;
      xv[0] = (k0 < K) ? *(const float4*)xr : float4{0.f, 0.f, 0.f, 0.f};
      xv[1] = (k0 + 4 < K) ? *(const float4*)(xr + 4)
                           : float4{0.f, 0.f, 0.f, 0.f};
    } else {
      av = *(const bf16x8*)(Ab + (rA >> 8) * sT + (rA & 255) * sB + k0);
    }
    #pragma unroll
    for (int q = 0; q < 3; ++q)
      bv[q] = *(const bf16x8*)(Bp + q * planeB + (n0 + cr) * (long)Kp + k0);
  };

  auto commit = [&]() {
    const int off = cr * LDW + cs;
    if constexpr (AF32) {
      bf16x8 h0, h1, h2;
      float t[8] = {xv[0].x, xv[0].y, xv[0].z, xv[0].w,
                    xv[1].x, xv[1].y, xv[1].z, xv[1].w};
      #pragma unroll
      for (int e = 0; e < 8; ++e) {
        bf16_t a, b, cc;
        split3(t[e], a, b, cc);
        h0[e] = a; h1[e] = b; h2[e] = cc;
      }
      *(bf16x8*)(&As[0][off]) = h0;
      *(bf16x8*)(&As[1][off]) = h1;
      *(bf16x8*)(&As[2][off]) = h2;
    } else {
      *(bf16x8*)(&As[0][off]) = av;
    }
    #pragma unroll
    for (int q = 0; q < 3; ++q) *(bf16x8*)(&Bs[q][off]) = bv[q];
  };

  const int numT = Kp / 32;
  prefetch(0);
  for (int kt = 0; kt < numT; ++kt) {
    __syncthreads();   // prior tile's frag reads done
    commit();
    const int kbn = (kt + 1 < numT) ? (kt + 1) * 32 : 0;  // harmless reload
    prefetch(kbn);     // next tile: global latency hides behind MFMA phase
    __syncthreads();   // staging visible

    // cache all A fragments once per tile (dedup across pb)
    bf16x8 afr[APL][2];
    #pragma unroll
    for (int pa = 0; pa < APL; ++pa)
      #pragma unroll
      for (int i = 0; i < 2; ++i)
        afr[pa][i] =
            *(const bf16x8*)(&As[pa][(wm + i * 16 + l16) * LDW + quad * 8]);

    #pragma unroll
    for (int pb = 0; pb < 3; ++pb) {
      bf16x8 bfr[4];
      #pragma unroll
      for (int j = 0; j < 4; ++j)
        bfr[j] =
            *(const bf16x8*)(&Bs[pb][(wn + j * 16 + l16) * LDW + quad * 8]);
      const int pamax = AF32 ? (2 - pb) : 0;  // pairs with pa+pb<=2
      #pragma unroll
      for (int pa = 0; pa < APL; ++pa) {
        if (pa > pamax) break;
        #pragma unroll
        for (int i = 0; i < 2; ++i)
          #pragma unroll
          for (int j = 0; j < 4; ++j)
            acc[i][j] = __builtin_amdgcn_mfma_f32_16x16x32_bf16(
                afr[pa][i], bfr[j], acc[i][j], 0, 0, 0);
      }
    }
  }

  // epilogue: C/D layout col=lane&15, row=quad*4+reg (m89/m91-verified)
  #pragma unroll
  for (int j = 0; j < 4; ++j) {
    const long col = n0 + wn + j * 16 + l16;
    const float bvv = bias[col];
    #pragma unroll
    for (int i = 0; i < 2; ++i) {
      const long row0 = m0 + wm + i * 16 + quad * 4;
      #pragma unroll
      for (int g = 0; g < 4; ++g)
        C[(row0 + g) * (long)N + col] = acc[i][j][g] + bvv;
    }
  }
}

// LIF scan, fp32 in -> bf16 spikes out (spikes {0,1} exact in bf16).
__global__ __launch_bounds__(256) void lif_scan_bf16(const float* __restrict__ I,
                                                     bf16_t* __restrict__ S) {
  int idx = blockIdx.x * 256 + threadIdx.x;
  float v = 0.f, cur = 0.f;
  #pragma unroll
  for (int t = 0; t < TT; ++t) {
    float inp = I[(long)t * (TB * TH) + idx];
    float vd = fmaf(0.05f, cur - v, v);
    float id = cur - 0.2f * cur;
    float s = (vd > 1.0f) ? 1.0f : 0.f;
    v = (1.0f - s) * vd;
    cur = id + inp;
    S[(long)t * (TB * TH) + idx] = (bf16_t)s;
  }
}

// GEMM3: one wave per row; I3[r][o] = S2[r][:] . Wout[o][:] + bout[o]
__global__ __launch_bounds__(256) void gemm3_kernel(
    const bf16_t* __restrict__ S2, const float* __restrict__ Wout,
    const float* __restrict__ bout, float* __restrict__ I3) {
  int wv = (blockIdx.x * blockDim.x + threadIdx.x) >> 6;
  int lane = threadIdx.x & 63;
  if (wv >= TM) return;
  const bf16_t* srow = S2 + (long)wv * TH;
  float acc[TOUT];
  #pragma unroll
  for (int o = 0; o < TOUT; ++o) acc[o] = 0.f;
  for (int k = lane; k < TH; k += 64) {
    float s = (float)srow[k];
    #pragma unroll
    for (int o = 0; o < TOUT; ++o) acc[o] = fmaf(s, Wout[o * TH + k], acc[o]);
  }
  #pragma unroll
  for (int off = 32; off > 0; off >>= 1)
    #pragma unroll
    for (int o = 0; o < TOUT; ++o) acc[o] += __shfl_down(acc[o], off, 64);
  if (lane == 0) {
    #pragma unroll
    for (int o = 0; o < TOUT; ++o) I3[(long)wv * TOUT + o] = acc[o] + bout[o];
  }
}

__global__ __launch_bounds__(256) void scan_out(const float* __restrict__ I3,
                                                float* __restrict__ out) {
  int idx = blockIdx.x * blockDim.x + threadIdx.x;
  if (idx >= TB * TOUT) return;
  float v = 0.f, cur = 0.f, cnt = 0.f;
  #pragma unroll
  for (int t = 0; t < TT; ++t) {
    float inp = I3[(long)t * (TB * TOUT) + idx];
    float vd = fmaf(0.05f, cur - v, v);
    float id = cur - 0.2f * cur;
    float s = (vd > 1.0f) ? 1.0f : 0.f;
    v = (1.0f - s) * vd;
    cur = id + inp;
    cnt += s;
  }
  out[idx] = cnt;
}

extern "C" void kernel_launch(void* const* d_in, const int* in_sizes, int n_in,
                              void* d_out, int out_size, void* d_ws,
                              size_t ws_size, hipStream_t stream) {
  const float* x    = (const float*)d_in[0];  // (256,32,2312)
  const float* W1   = (const float*)d_in[1];  // (1024,2312)
  const float* b1   = (const float*)d_in[2];
  const float* W2   = (const float*)d_in[3];  // (1024,1024)
  const float* b2   = (const float*)d_in[4];
  const float* Wout = (const float*)d_in[5];  // (10,1024)
  const float* bout = (const float*)d_in[6];

  // ws: W1p 14.55MB | W2p 6.29MB | bufI 33.55MB | S1 16.78MB | buf3 0.33MB
  // S2 (16.78MB) ALIASES W1p/W2p: planes are last read by GEMM2, S2 is
  // written by the later scan (stream-sequential => safe; rebuilt each call).
  bf16_t* W1p  = (bf16_t*)d_ws;
  bf16_t* W2p  = W1p + 3L * TH * KP1;
  float*  bufI = (float*)(W2p + 3L * TH * TH);
  bf16_t* S1   = (bf16_t*)(bufI + (long)TM * TH);
  float*  buf3 = (float*)(S1 + (long)TM * TH);
  bf16_t* S2   = (bf16_t*)d_ws;

  split_w<<<dim3(3, TH), 256, 0, stream>>>(W1, W1p, (long)TH * KP1, TIN, KP1);
  split_w<<<dim3(1, TH), 256, 0, stream>>>(W2, W2p, (long)TH * TH, TH, TH);

  // GEMM1: row r=(t,b): x offset = t*2312 + b*(32*2312)
  snn_gemm<true><<<dim3(TM / 128, TH / 128), 512, 0, stream>>>(
      x, nullptr, (long)TIN, (long)TT * TIN, W1p, (long)TH * KP1, KP1, TIN, b1,
      bufI, TH);

  lif_scan_bf16<<<(TB * TH) / 256, 256, 0, stream>>>(bufI, S1);

  // GEMM2: S1 row-major [8192][1024]: sT=256*1024, sB=1024
  snn_gemm<false><<<dim3(TM / 128, TH / 128), 512, 0, stream>>>(
      nullptr, S1, (long)TB * TH, (long)TH, W2p, (long)TH * TH, TH, TH, b2,
      bufI, TH);

  lif_scan_bf16<<<(TB * TH) / 256, 256, 0, stream>>>(bufI, S2);

  gemm3_kernel<<<(TM * 64) / 256, 256, 0, stream>>>(S2, Wout, bout, buf3);

  scan_out<<<(TB * TOUT + 255) / 256, 256, 0, stream>>>(buf3, (float*)d_out);
}

// Round 2
// 334.940 us; speedup vs baseline: 1.2526x; 1.2526x over previous
//
#include <hip/hip_runtime.h>

// SNN: 3-layer LIF, B=256, T=32, H=1024, IN=2312, OUT=10.
// Round-4: 512-thread / 8-wave GEMM blocks (occupancy 21.5->37.9%) -- time
//   flat: per-pipe model showed LDS pipe 59%+ / MFMA 48% / VALU 29%, all
//   coupled by the 6-pass bf16 split (no single pipe saturated).
// Round-5: GEMM1 switches to fp16 2-plane split, 3 passes (a0b0,a0b1,a1b0).
//   fp16's 11-bit mantissa makes 2 planes ~ bf16's 3: error bound 2^-20.4
//   vs 2^-22.4 (both ~fp32 accumulation noise on I1 ~ 0.3). Cuts GEMM1
//   MFMA work 50%, LDS fragment traffic 33%, commit VALU 40%, LDS
//   footprint 55296->36864 B. GEMM2 stays bf16-3-plane (spikes exact in
//   bf16; error unchanged there). If absmax != 0, revert to 4/6-pass.

#define TB 256
#define TT 32
#define TH 1024
#define TIN 2312
#define TOUT 10
#define TM (TT * TB)   // 8192 rows = (t,b)
#define KP1 2368       // TIN padded to multiple of 32

typedef __bf16 bf16_t;
typedef bf16_t bf16x8 __attribute__((ext_vector_type(8)));
typedef bf16_t bf16x4 __attribute__((ext_vector_type(4)));
typedef _Float16 f16_t;
typedef f16_t f16x8 __attribute__((ext_vector_type(8)));
typedef f16_t f16x4 __attribute__((ext_vector_type(4)));
typedef float floatx4 __attribute__((ext_vector_type(4)));

__device__ __forceinline__ void split3(float v, bf16_t& a, bf16_t& b, bf16_t& c) {
  a = (bf16_t)v;
  float r1 = v - (float)a;
  b = (bf16_t)r1;
  c = (bf16_t)(r1 - (float)b);
}

__device__ __forceinline__ void split2h(float v, f16_t& a, f16_t& b) {
  a = (f16_t)v;
  b = (f16_t)(v - (float)a);
}

// W (rows x K) -> 3 bf16 planes (rows x Kp), zero-padded K..Kp.
__global__ __launch_bounds__(256) void split_w(const float* __restrict__ W,
                                               bf16_t* __restrict__ P,
                                               long plane, int K, int Kp) {
  int k4 = (blockIdx.x * 256 + threadIdx.x) * 4;
  if (k4 >= Kp) return;
  long r = blockIdx.y;
  float4 v = (k4 < K) ? *(const float4*)(W + r * (long)K + k4)
                      : float4{0.f, 0.f, 0.f, 0.f};
  float t[4] = {v.x, v.y, v.z, v.w};
  bf16x4 a, b, c;
  #pragma unroll
  for (int e = 0; e < 4; ++e) {
    bf16_t x, y, z;
    split3(t[e], x, y, z);
    a[e] = x; b[e] = y; c[e] = z;
  }
  long o = r * (long)Kp + k4;
  *(bf16x4*)(P + o) = a;
  *(bf16x4*)(P + plane + o) = b;
  *(bf16x4*)(P + 2 * plane + o) = c;
}

// W (rows x K) -> 2 fp16 planes (rows x Kp), zero-padded K..Kp.
__global__ __launch_bounds__(256) void split_w1h(const float* __restrict__ W,
                                                 f16_t* __restrict__ P,
                                                 long plane, int K, int Kp) {
  int k4 = (blockIdx.x * 256 + threadIdx.x) * 4;
  if (k4 >= Kp) return;
  long r = blockIdx.y;
  float4 v = (k4 < K) ? *(const float4*)(W + r * (long)K + k4)
                      : float4{0.f, 0.f, 0.f, 0.f};
  float t[4] = {v.x, v.y, v.z, v.w};
  f16x4 a, b;
  #pragma unroll
  for (int e = 0; e < 4; ++e) {
    f16_t x, y;
    split2h(t[e], x, y);
    a[e] = x; b[e] = y;
  }
  long o = r * (long)Kp + k4;
  *(f16x4*)(P + o) = a;
  *(f16x4*)(P + plane + o) = b;
}

// GEMM1: C[r][n] = sum over 3 fp16 passes of A(x fp32, split in-kernel) x
// B(W1 fp16 2-plane) + bias. A row element offset = (r>>8)*sT + (r&255)*sB.
// 512 threads = 8 waves laid out 4(M) x 2(N); per-wave 32x64 output.
__global__ __launch_bounds__(512, 4) void snn_gemm1(
    const float* __restrict__ Af, long sT, long sB,
    const f16_t* __restrict__ Bp, long planeB, int Kp, int K,
    const float* __restrict__ bias, float* __restrict__ C, int N) {
  constexpr int LDW = 36;  // 32 + 4 pad: breaks power-of-2 row stride
  __shared__ f16_t As[2][128 * LDW];
  __shared__ f16_t Bs[2][128 * LDW];

  const int tid = threadIdx.x;
  const int wave = tid >> 6, lane = tid & 63;
  const int quad = lane >> 4, l16 = lane & 15;
  const int wm = (wave & 3) * 32, wn = (wave >> 2) * 64;
  const long m0 = (long)blockIdx.x * 128, n0 = (long)blockIdx.y * 128;

  floatx4 acc[2][4];
  #pragma unroll
  for (int i = 0; i < 2; ++i)
    #pragma unroll
    for (int j = 0; j < 4; ++j) acc[i][j] = (floatx4){0.f, 0.f, 0.f, 0.f};

  const int cr = tid >> 2;        // tile row 0..127
  const int cs = (tid & 3) * 8;   // K-seg elem offset 0/8/16/24
  float4 xv[2];
  f16x8 bv[2];

  auto prefetch = [&](int kb) {
    const long rA = m0 + cr;
    const int k0 = kb + cs;
    const float* xr = Af + (rA >> 8) * sT + (rA & 255) * sB + k0;
    xv[0] = (k0 < K) ? *(const float4*)xr : float4{0.f, 0.f, 0.f, 0.f};
    xv[1] = (k0 + 4 < K) ? *(const float4*)(xr + 4)
                         : float4{0.f, 0.f, 0.f, 0.f};
    #pragma unroll
    for (int q = 0; q < 2; ++q)
      bv[q] = *(const f16x8*)(Bp + q * planeB + (n0 + cr) * (long)Kp + k0);
  };

  auto commit = [&]() {
    const int off = cr * LDW + cs;
    f16x8 h0, h1;
    float t[8] = {xv[0].x, xv[0].y, xv[0].z, xv[0].w,
                  xv[1].x, xv[1].y, xv[1].z, xv[1].w};
    #pragma unroll
    for (int e = 0; e < 8; ++e) {
      f16_t a, b;
      split2h(t[e], a, b);
      h0[e] = a; h1[e] = b;
    }
    *(f16x8*)(&As[0][off]) = h0;
    *(f16x8*)(&As[1][off]) = h1;
    #pragma unroll
    for (int q = 0; q < 2; ++q) *(f16x8*)(&Bs[q][off]) = bv[q];
  };

  const int numT = Kp / 32;
  prefetch(0);
  for (int kt = 0; kt < numT; ++kt) {
    __syncthreads();   // prior tile's frag reads done
    commit();
    const int kbn = (kt + 1 < numT) ? (kt + 1) * 32 : 0;  // harmless reload
    prefetch(kbn);     // next tile: global latency hides behind MFMA phase
    __syncthreads();   // staging visible

    f16x8 afr[2][2];
    #pragma unroll
    for (int pa = 0; pa < 2; ++pa)
      #pragma unroll
      for (int i = 0; i < 2; ++i)
        afr[pa][i] =
            *(const f16x8*)(&As[pa][(wm + i * 16 + l16) * LDW + quad * 8]);

    #pragma unroll
    for (int pb = 0; pb < 2; ++pb) {
      f16x8 bfr[4];
      #pragma unroll
      for (int j = 0; j < 4; ++j)
        bfr[j] =
            *(const f16x8*)(&Bs[pb][(wn + j * 16 + l16) * LDW + quad * 8]);
      const int pamax = 1 - pb;  // pairs with pa+pb<=1: (0,0),(1,0),(0,1)
      #pragma unroll
      for (int pa = 0; pa < 2; ++pa) {
        if (pa > pamax) break;
        #pragma unroll
        for (int i = 0; i < 2; ++i)
          #pragma unroll
          for (int j = 0; j < 4; ++j)
            acc[i][j] = __builtin_amdgcn_mfma_f32_16x16x32_f16(
                afr[pa][i], bfr[j], acc[i][j], 0, 0, 0);
      }
    }
  }

  // epilogue: C/D layout col=lane&15, row=quad*4+reg (dtype-independent)
  #pragma unroll
  for (int j = 0; j < 4; ++j) {
    const long col = n0 + wn + j * 16 + l16;
    const float bvv = bias[col];
    #pragma unroll
    for (int i = 0; i < 2; ++i) {
      const long row0 = m0 + wm + i * 16 + quad * 4;
      #pragma unroll
      for (int g = 0; g < 4; ++g)
        C[(row0 + g) * (long)N + col] = acc[i][j][g] + bvv;
    }
  }
}

// GEMM2: A = spikes (bf16 exact, 1 plane), B = W2 bf16 3-plane, 3 passes.
__global__ __launch_bounds__(512, 4) void snn_gemm2(
    const bf16_t* __restrict__ Ab, long sT, long sB,
    const bf16_t* __restrict__ Bp, long planeB, int Kp,
    const float* __restrict__ bias, float* __restrict__ C, int N) {
  constexpr int LDW = 36;
  __shared__ bf16_t As[1][128 * LDW];
  __shared__ bf16_t Bs[3][128 * LDW];

  const int tid = threadIdx.x;
  const int wave = tid >> 6, lane = tid & 63;
  const int quad = lane >> 4, l16 = lane & 15;
  const int wm = (wave & 3) * 32, wn = (wave >> 2) * 64;
  const long m0 = (long)blockIdx.x * 128, n0 = (long)blockIdx.y * 128;

  floatx4 acc[2][4];
  #pragma unroll
  for (int i = 0; i < 2; ++i)
    #pragma unroll
    for (int j = 0; j < 4; ++j) acc[i][j] = (floatx4){0.f, 0.f, 0.f, 0.f};

  const int cr = tid >> 2;
  const int cs = (tid & 3) * 8;
  bf16x8 av;
  bf16x8 bv[3];

  auto prefetch = [&](int kb) {
    const long rA = m0 + cr;
    const int k0 = kb + cs;
    av = *(const bf16x8*)(Ab + (rA >> 8) * sT + (rA & 255) * sB + k0);
    #pragma unroll
    for (int q = 0; q < 3; ++q)
      bv[q] = *(const bf16x8*)(Bp + q * planeB + (n0 + cr) * (long)Kp + k0);
  };

  auto commit = [&]() {
    const int off = cr * LDW + cs;
    *(bf16x8*)(&As[0][off]) = av;
    #pragma unroll
    for (int q = 0; q < 3; ++q) *(bf16x8*)(&Bs[q][off]) = bv[q];
  };

  const int numT = Kp / 32;
  prefetch(0);
  for (int kt = 0; kt < numT; ++kt) {
    __syncthreads();
    commit();
    const int kbn = (kt + 1 < numT) ? (kt + 1) * 32 : 0;
    prefetch(kbn);
    __syncthreads();

    bf16x8 afr[2];
    #pragma unroll
    for (int i = 0; i < 2; ++i)
      afr[i] = *(const bf16x8*)(&As[0][(wm + i * 16 + l16) * LDW + quad * 8]);

    #pragma unroll
    for (int pb = 0; pb < 3; ++pb) {
      bf16x8 bfr[4];
      #pragma unroll
      for (int j = 0; j < 4; ++j)
        bfr[j] =
            *(const bf16x8*)(&Bs[pb][(wn + j * 16 + l16) * LDW + quad * 8]);
      #pragma unroll
      for (int i = 0; i < 2; ++i)
        #pragma unroll
        for (int j = 0; j < 4; ++j)
          acc[i][j] = __builtin_amdgcn_mfma_f32_16x16x32_bf16(
              afr[i], bfr[j], acc[i][j], 0, 0, 0);
    }
  }

  #pragma unroll
  for (int j = 0; j < 4; ++j) {
    const long col = n0 + wn + j * 16 + l16;
    const float bvv = bias[col];
    #pragma unroll
    for (int i = 0; i < 2; ++i) {
      const long row0 = m0 + wm + i * 16 + quad * 4;
      #pragma unroll
      for (int g = 0; g < 4; ++g)
        C[(row0 + g) * (long)N + col] = acc[i][j][g] + bvv;
    }
  }
}

// LIF scan, fp32 in -> bf16 spikes out (spikes {0,1} exact in bf16).
__global__ __launch_bounds__(256) void lif_scan_bf16(const float* __restrict__ I,
                                                     bf16_t* __restrict__ S) {
  int idx = blockIdx.x * 256 + threadIdx.x;
  float v = 0.f, cur = 0.f;
  #pragma unroll
  for (int t = 0; t < TT; ++t) {
    float inp = I[(long)t * (TB * TH) + idx];
    float vd = fmaf(0.05f, cur - v, v);
    float id = cur - 0.2f * cur;
    float s = (vd > 1.0f) ? 1.0f : 0.f;
    v = (1.0f - s) * vd;
    cur = id + inp;
    S[(long)t * (TB * TH) + idx] = (bf16_t)s;
  }
}

// GEMM3: one wave per row; I3[r][o] = S2[r][:] . Wout[o][:] + bout[o]
__global__ __launch_bounds__(256) void gemm3_kernel(
    const bf16_t* __restrict__ S2, const float* __restrict__ Wout,
    const float* __restrict__ bout, float* __restrict__ I3) {
  int wv = (blockIdx.x * blockDim.x + threadIdx.x) >> 6;
  int lane = threadIdx.x & 63;
  if (wv >= TM) return;
  const bf16_t* srow = S2 + (long)wv * TH;
  float acc[TOUT];
  #pragma unroll
  for (int o = 0; o < TOUT; ++o) acc[o] = 0.f;
  for (int k = lane; k < TH; k += 64) {
    float s = (float)srow[k];
    #pragma unroll
    for (int o = 0; o < TOUT; ++o) acc[o] = fmaf(s, Wout[o * TH + k], acc[o]);
  }
  #pragma unroll
  for (int off = 32; off > 0; off >>= 1)
    #pragma unroll
    for (int o = 0; o < TOUT; ++o) acc[o] += __shfl_down(acc[o], off, 64);
  if (lane == 0) {
    #pragma unroll
    for (int o = 0; o < TOUT; ++o) I3[(long)wv * TOUT + o] = acc[o] + bout[o];
  }
}

__global__ __launch_bounds__(256) void scan_out(const float* __restrict__ I3,
                                                float* __restrict__ out) {
  int idx = blockIdx.x * blockDim.x + threadIdx.x;
  if (idx >= TB * TOUT) return;
  float v = 0.f, cur = 0.f, cnt = 0.f;
  #pragma unroll
  for (int t = 0; t < TT; ++t) {
    float inp = I3[(long)t * (TB * TOUT) + idx];
    float vd = fmaf(0.05f, cur - v, v);
    float id = cur - 0.2f * cur;
    float s = (vd > 1.0f) ? 1.0f : 0.f;
    v = (1.0f - s) * vd;
    cur = id + inp;
    cnt += s;
  }
  out[idx] = cnt;
}

extern "C" void kernel_launch(void* const* d_in, const int* in_sizes, int n_in,
                              void* d_out, int out_size, void* d_ws,
                              size_t ws_size, hipStream_t stream) {
  const float* x    = (const float*)d_in[0];  // (256,32,2312)
  const float* W1   = (const float*)d_in[1];  // (1024,2312)
  const float* b1   = (const float*)d_in[2];
  const float* W2   = (const float*)d_in[3];  // (1024,1024)
  const float* b2   = (const float*)d_in[4];
  const float* Wout = (const float*)d_in[5];  // (10,1024)
  const float* bout = (const float*)d_in[6];

  // ws layout (bytes):
  //   [0, 16.78M)      : W1p (fp16 2-plane, 9.70M) + W2p (bf16 3-plane,
  //                      6.29M) -- both dead after GEMM2; S2 (bf16, 16.78M)
  //                      ALIASES this whole region (stream-sequential safe;
  //                      planes rebuilt each call).
  //   [16.78M, 50.33M) : bufI (fp32, 33.55M)
  //   [50.33M, 67.11M) : S1 (bf16, 16.78M)
  //   [67.11M, 67.44M) : buf3 (fp32, 0.33M)
  char* base = (char*)d_ws;
  const long S2_BYTES = (long)TM * TH * 2;  // 16,777,216
  f16_t*  W1p  = (f16_t*)base;
  bf16_t* W2p  = (bf16_t*)(base + 2L * TH * KP1 * 2);   // after 9,699,328 B
  float*  bufI = (float*)(base + S2_BYTES);
  bf16_t* S1   = (bf16_t*)(base + S2_BYTES + (long)TM * TH * 4);
  float*  buf3 = (float*)(base + S2_BYTES + (long)TM * TH * 4 + (long)TM * TH * 2);
  bf16_t* S2   = (bf16_t*)base;

  split_w1h<<<dim3(3, TH), 256, 0, stream>>>(W1, W1p, (long)TH * KP1, TIN, KP1);
  split_w<<<dim3(1, TH), 256, 0, stream>>>(W2, W2p, (long)TH * TH, TH, TH);

  // GEMM1: row r=(t,b): x offset = t*2312 + b*(32*2312)
  snn_gemm1<<<dim3(TM / 128, TH / 128), 512, 0, stream>>>(
      x, (long)TIN, (long)TT * TIN, W1p, (long)TH * KP1, KP1, TIN, b1, bufI,
      TH);

  lif_scan_bf16<<<(TB * TH) / 256, 256, 0, stream>>>(bufI, S1);

  // GEMM2: S1 row-major [8192][1024]: sT=256*1024, sB=1024
  snn_gemm2<<<dim3(TM / 128, TH / 128), 512, 0, stream>>>(
      S1, (long)TB * TH, (long)TH, W2p, (long)TH * TH, TH, b2, bufI, TH);

  lif_scan_bf16<<<(TB * TH) / 256, 256, 0, stream>>>(bufI, S2);

  gemm3_kernel<<<(TM * 64) / 256, 256, 0, stream>>>(S2, Wout, bout, buf3);

  scan_out<<<(TB * TOUT + 255) / 256, 256, 0, stream>>>(buf3, (float*)d_out);
}

// Round 3
// 331.998 us; speedup vs baseline: 1.2637x; 1.0089x over previous
//
#include <hip/hip_runtime.h>

// SNN: 3-layer LIF, B=256, T=32, H=1024, IN=2312, OUT=10.
// Round-5: GEMM1 fp16 2-plane split, 3 passes (absmax 0.0 validated).
// Round-6: LDS-pipe relief. Per-CU model at r5: LDS 227k cyc (62%) vs
//   MFMA 138k (37%) -- fragment reads dominate. Changes:
//   (a) per-wave 64x64 tiles (BM=128, BN=256, 8 waves 2Mx4N): reads/MFMA
//       0.5 -> 0.33, LDS/CU -> ~156k; grid_N 8->4 halves A-split VALU.
//   (b) GEMM2: W2 as fp16 2-plane, 2 passes (spikes exact in fp16, so
//       a*b0 + a*b1 = a*(b0+b1): no dropped term; weight precision 22 bit).
//   Occupancy drops to 8 waves/CU (25%) -- deliberate: round-4 proved
//   occupancy alone is not the lever; pipe floors are.

#define TB 256
#define TT 32
#define TH 1024
#define TIN 2312
#define TOUT 10
#define TM (TT * TB)   // 8192 rows = (t,b)
#define KP1 2368       // TIN padded to multiple of 32

typedef _Float16 f16_t;
typedef f16_t f16x8 __attribute__((ext_vector_type(8)));
typedef f16_t f16x4 __attribute__((ext_vector_type(4)));
typedef float floatx4 __attribute__((ext_vector_type(4)));

__device__ __forceinline__ void split2h(float v, f16_t& a, f16_t& b) {
  a = (f16_t)v;
  b = (f16_t)(v - (float)a);
}

// W (rows x K) -> 2 fp16 planes (rows x Kp), zero-padded K..Kp.
__global__ __launch_bounds__(256) void split_w1h(const float* __restrict__ W,
                                                 f16_t* __restrict__ P,
                                                 long plane, int K, int Kp) {
  int k4 = (blockIdx.x * 256 + threadIdx.x) * 4;
  if (k4 >= Kp) return;
  long r = blockIdx.y;
  float4 v = (k4 < K) ? *(const float4*)(W + r * (long)K + k4)
                      : float4{0.f, 0.f, 0.f, 0.f};
  float t[4] = {v.x, v.y, v.z, v.w};
  f16x4 a, b;
  #pragma unroll
  for (int e = 0; e < 4; ++e) {
    f16_t x, y;
    split2h(t[e], x, y);
    a[e] = x; b[e] = y;
  }
  long o = r * (long)Kp + k4;
  *(f16x4*)(P + o) = a;
  *(f16x4*)(P + plane + o) = b;
}

// GEMM1: C[r][n] = 3 fp16 passes of A(x fp32, split in-kernel) x
// B(W1 fp16 2-plane) + bias. A row elem offset = (r>>8)*sT + (r&255)*sB.
// Block tile 128(M) x 256(N), BK=32; 8 waves 2(M)x4(N), per-wave 64x64.
__global__ __launch_bounds__(512, 2) void snn_gemm1(
    const float* __restrict__ Af, long sT, long sB,
    const f16_t* __restrict__ Bp, long planeB, int Kp, int K,
    const float* __restrict__ bias, float* __restrict__ C, int N) {
  constexpr int LDW = 36;  // 32 + 4 pad: 72B row stride -> 16 distinct
                           // even bank starts for l16 frag reads
  __shared__ f16_t As[2][128 * LDW];
  __shared__ f16_t Bs[2][256 * LDW];

  const int tid = threadIdx.x;
  const int wave = tid >> 6, lane = tid & 63;
  const int quad = lane >> 4, l16 = lane & 15;
  const int wm = (wave & 1) * 64, wn = (wave >> 1) * 64;
  const long m0 = (long)blockIdx.x * 128, n0 = (long)blockIdx.y * 256;

  floatx4 acc[4][4];
  #pragma unroll
  for (int i = 0; i < 4; ++i)
    #pragma unroll
    for (int j = 0; j < 4; ++j) acc[i][j] = (floatx4){0.f, 0.f, 0.f, 0.f};

  // A staging: thread owns (row cr, 8-elem seg cs); B: (row crB, 16-elem seg)
  const int cr = tid >> 2;        // 0..127
  const int cs = (tid & 3) * 8;   // 0/8/16/24
  const int crB = tid >> 1;       // 0..255
  const int csB = (tid & 1) * 16; // 0/16
  float4 xv[2];
  f16x8 bv[2][2];

  auto prefetch = [&](int kb) {
    const long rA = m0 + cr;
    const int k0 = kb + cs;
    const float* xr = Af + (rA >> 8) * sT + (rA & 255) * sB + k0;
    xv[0] = (k0 < K) ? *(const float4*)xr : float4{0.f, 0.f, 0.f, 0.f};
    xv[1] = (k0 + 4 < K) ? *(const float4*)(xr + 4)
                         : float4{0.f, 0.f, 0.f, 0.f};
    const int kB = kb + csB;
    #pragma unroll
    for (int q = 0; q < 2; ++q) {
      const f16_t* br = Bp + q * planeB + (n0 + crB) * (long)Kp + kB;
      bv[q][0] = *(const f16x8*)br;
      bv[q][1] = *(const f16x8*)(br + 8);
    }
  };

  auto commit = [&]() {
    const int off = cr * LDW + cs;
    f16x8 h0, h1;
    float t[8] = {xv[0].x, xv[0].y, xv[0].z, xv[0].w,
                  xv[1].x, xv[1].y, xv[1].z, xv[1].w};
    #pragma unroll
    for (int e = 0; e < 8; ++e) {
      f16_t a, b;
      split2h(t[e], a, b);
      h0[e] = a; h1[e] = b;
    }
    *(f16x8*)(&As[0][off]) = h0;
    *(f16x8*)(&As[1][off]) = h1;
    const int offB = crB * LDW + csB;
    #pragma unroll
    for (int q = 0; q < 2; ++q) {
      *(f16x8*)(&Bs[q][offB]) = bv[q][0];
      *(f16x8*)(&Bs[q][offB + 8]) = bv[q][1];
    }
  };

  const int numT = Kp / 32;
  prefetch(0);
  for (int kt = 0; kt < numT; ++kt) {
    __syncthreads();   // prior tile's frag reads done
    commit();
    const int kbn = (kt + 1 < numT) ? (kt + 1) * 32 : 0;  // harmless reload
    prefetch(kbn);     // next-tile loads fly during MFMA phase
    __syncthreads();   // staging visible

    f16x8 afr[2][4];
    #pragma unroll
    for (int pa = 0; pa < 2; ++pa)
      #pragma unroll
      for (int i = 0; i < 4; ++i)
        afr[pa][i] =
            *(const f16x8*)(&As[pa][(wm + i * 16 + l16) * LDW + quad * 8]);

    #pragma unroll
    for (int pb = 0; pb < 2; ++pb) {
      f16x8 bfr[4];
      #pragma unroll
      for (int j = 0; j < 4; ++j)
        bfr[j] =
            *(const f16x8*)(&Bs[pb][(wn + j * 16 + l16) * LDW + quad * 8]);
      const int pamax = 1 - pb;  // passes (0,0),(1,0),(0,1)
      #pragma unroll
      for (int pa = 0; pa < 2; ++pa) {
        if (pa > pamax) break;
        #pragma unroll
        for (int i = 0; i < 4; ++i)
          #pragma unroll
          for (int j = 0; j < 4; ++j)
            acc[i][j] = __builtin_amdgcn_mfma_f32_16x16x32_f16(
                afr[pa][i], bfr[j], acc[i][j], 0, 0, 0);
      }
    }
  }

  // epilogue: C/D layout col=lane&15, row=quad*4+reg (dtype-independent)
  #pragma unroll
  for (int j = 0; j < 4; ++j) {
    const long col = n0 + wn + j * 16 + l16;
    const float bvv = bias[col];
    #pragma unroll
    for (int i = 0; i < 4; ++i) {
      const long row0 = m0 + wm + i * 16 + quad * 4;
      #pragma unroll
      for (int g = 0; g < 4; ++g)
        C[(row0 + g) * (long)N + col] = acc[i][j][g] + bvv;
    }
  }
}

// GEMM2: A = spikes (fp16 exact, 1 plane), B = W2 fp16 2-plane, 2 passes
// (a*b0 + a*b1 = a*(b0+b1): nothing dropped). Same tile geometry as GEMM1.
__global__ __launch_bounds__(512, 2) void snn_gemm2(
    const f16_t* __restrict__ Ab, long sT, long sB,
    const f16_t* __restrict__ Bp, long planeB, int Kp,
    const float* __restrict__ bias, float* __restrict__ C, int N) {
  constexpr int LDW = 36;
  __shared__ f16_t As[128 * LDW];
  __shared__ f16_t Bs[2][256 * LDW];

  const int tid = threadIdx.x;
  const int wave = tid >> 6, lane = tid & 63;
  const int quad = lane >> 4, l16 = lane & 15;
  const int wm = (wave & 1) * 64, wn = (wave >> 1) * 64;
  const long m0 = (long)blockIdx.x * 128, n0 = (long)blockIdx.y * 256;

  floatx4 acc[4][4];
  #pragma unroll
  for (int i = 0; i < 4; ++i)
    #pragma unroll
    for (int j = 0; j < 4; ++j) acc[i][j] = (floatx4){0.f, 0.f, 0.f, 0.f};

  const int cr = tid >> 2;
  const int cs = (tid & 3) * 8;
  const int crB = tid >> 1;
  const int csB = (tid & 1) * 16;
  f16x8 av;
  f16x8 bv[2][2];

  auto prefetch = [&](int kb) {
    const long rA = m0 + cr;
    av = *(const f16x8*)(Ab + (rA >> 8) * sT + (rA & 255) * sB + kb + cs);
    const int kB = kb + csB;
    #pragma unroll
    for (int q = 0; q < 2; ++q) {
      const f16_t* br = Bp + q * planeB + (n0 + crB) * (long)Kp + kB;
      bv[q][0] = *(const f16x8*)br;
      bv[q][1] = *(const f16x8*)(br + 8);
    }
  };

  auto commit = [&]() {
    *(f16x8*)(&As[cr * LDW + cs]) = av;
    const int offB = crB * LDW + csB;
    #pragma unroll
    for (int q = 0; q < 2; ++q) {
      *(f16x8*)(&Bs[q][offB]) = bv[q][0];
      *(f16x8*)(&Bs[q][offB + 8]) = bv[q][1];
    }
  };

  const int numT = Kp / 32;
  prefetch(0);
  for (int kt = 0; kt < numT; ++kt) {
    __syncthreads();
    commit();
    const int kbn = (kt + 1 < numT) ? (kt + 1) * 32 : 0;
    prefetch(kbn);
    __syncthreads();

    f16x8 afr[4];
    #pragma unroll
    for (int i = 0; i < 4; ++i)
      afr[i] = *(const f16x8*)(&As[(wm + i * 16 + l16) * LDW + quad * 8]);

    #pragma unroll
    for (int pb = 0; pb < 2; ++pb) {
      f16x8 bfr[4];
      #pragma unroll
      for (int j = 0; j < 4; ++j)
        bfr[j] =
            *(const f16x8*)(&Bs[pb][(wn + j * 16 + l16) * LDW + quad * 8]);
      #pragma unroll
      for (int i = 0; i < 4; ++i)
        #pragma unroll
        for (int j = 0; j < 4; ++j)
          acc[i][j] = __builtin_amdgcn_mfma_f32_16x16x32_f16(
              afr[i], bfr[j], acc[i][j], 0, 0, 0);
    }
  }

  #pragma unroll
  for (int j = 0; j < 4; ++j) {
    const long col = n0 + wn + j * 16 + l16;
    const float bvv = bias[col];
    #pragma unroll
    for (int i = 0; i < 4; ++i) {
      const long row0 = m0 + wm + i * 16 + quad * 4;
      #pragma unroll
      for (int g = 0; g < 4; ++g)
        C[(row0 + g) * (long)N + col] = acc[i][j][g] + bvv;
    }
  }
}

// LIF scan, fp32 in -> fp16 spikes out (spikes {0,1} exact in fp16).
__global__ __launch_bounds__(256) void lif_scan_f16(const float* __restrict__ I,
                                                    f16_t* __restrict__ S) {
  int idx = blockIdx.x * 256 + threadIdx.x;
  float v = 0.f, cur = 0.f;
  #pragma unroll
  for (int t = 0; t < TT; ++t) {
    float inp = I[(long)t * (TB * TH) + idx];
    float vd = fmaf(0.05f, cur - v, v);
    float id = cur - 0.2f * cur;
    float s = (vd > 1.0f) ? 1.0f : 0.f;
    v = (1.0f - s) * vd;
    cur = id + inp;
    S[(long)t * (TB * TH) + idx] = (f16_t)s;
  }
}

// GEMM3: one wave per row; I3[r][o] = S2[r][:] . Wout[o][:] + bout[o]
__global__ __launch_bounds__(256) void gemm3_kernel(
    const f16_t* __restrict__ S2, const float* __restrict__ Wout,
    const float* __restrict__ bout, float* __restrict__ I3) {
  int wv = (blockIdx.x * blockDim.x + threadIdx.x) >> 6;
  int lane = threadIdx.x & 63;
  if (wv >= TM) return;
  const f16_t* srow = S2 + (long)wv * TH;
  float acc[TOUT];
  #pragma unroll
  for (int o = 0; o < TOUT; ++o) acc[o] = 0.f;
  for (int k = lane; k < TH; k += 64) {
    float s = (float)srow[k];
    #pragma unroll
    for (int o = 0; o < TOUT; ++o) acc[o] = fmaf(s, Wout[o * TH + k], acc[o]);
  }
  #pragma unroll
  for (int off = 32; off > 0; off >>= 1)
    #pragma unroll
    for (int o = 0; o < TOUT; ++o) acc[o] += __shfl_down(acc[o], off, 64);
  if (lane == 0) {
    #pragma unroll
    for (int o = 0; o < TOUT; ++o) I3[(long)wv * TOUT + o] = acc[o] + bout[o];
  }
}

__global__ __launch_bounds__(256) void scan_out(const float* __restrict__ I3,
                                                float* __restrict__ out) {
  int idx = blockIdx.x * blockDim.x + threadIdx.x;
  if (idx >= TB * TOUT) return;
  float v = 0.f, cur = 0.f, cnt = 0.f;
  #pragma unroll
  for (int t = 0; t < TT; ++t) {
    float inp = I3[(long)t * (TB * TOUT) + idx];
    float vd = fmaf(0.05f, cur - v, v);
    float id = cur - 0.2f * cur;
    float s = (vd > 1.0f) ? 1.0f : 0.f;
    v = (1.0f - s) * vd;
    cur = id + inp;
    cnt += s;
  }
  out[idx] = cnt;
}

extern "C" void kernel_launch(void* const* d_in, const int* in_sizes, int n_in,
                              void* d_out, int out_size, void* d_ws,
                              size_t ws_size, hipStream_t stream) {
  const float* x    = (const float*)d_in[0];  // (256,32,2312)
  const float* W1   = (const float*)d_in[1];  // (1024,2312)
  const float* b1   = (const float*)d_in[2];
  const float* W2   = (const float*)d_in[3];  // (1024,1024)
  const float* b2   = (const float*)d_in[4];
  const float* Wout = (const float*)d_in[5];  // (10,1024)
  const float* bout = (const float*)d_in[6];

  // ws layout (bytes):
  //   [0, 16.78M)      : W1p (fp16 2-plane, 9.70M) + W2p (fp16 2-plane,
  //                      4.19M) -- dead after GEMM2; S2 (fp16, 16.78M)
  //                      ALIASES this region (stream-sequential safe;
  //                      planes rebuilt each call).
  //   [16.78M, 50.33M) : bufI (fp32, 33.55M)
  //   [50.33M, 67.11M) : S1 (fp16, 16.78M)
  //   [67.11M, 67.44M) : buf3 (fp32, 0.33M)
  char* base = (char*)d_ws;
  const long S2_BYTES = (long)TM * TH * 2;  // 16,777,216
  f16_t* W1p  = (f16_t*)base;
  f16_t* W2p  = (f16_t*)(base + 2L * TH * KP1 * 2);  // after 9,699,328 B
  float* bufI = (float*)(base + S2_BYTES);
  f16_t* S1   = (f16_t*)(base + S2_BYTES + (long)TM * TH * 4);
  float* buf3 = (float*)(base + S2_BYTES + (long)TM * TH * 4 + (long)TM * TH * 2);
  f16_t* S2   = (f16_t*)base;

  split_w1h<<<dim3(3, TH), 256, 0, stream>>>(W1, W1p, (long)TH * KP1, TIN, KP1);
  split_w1h<<<dim3(1, TH), 256, 0, stream>>>(W2, W2p, (long)TH * TH, TH, TH);

  // GEMM1: row r=(t,b): x offset = t*2312 + b*(32*2312)
  snn_gemm1<<<dim3(TM / 128, TH / 256), 512, 0, stream>>>(
      x, (long)TIN, (long)TT * TIN, W1p, (long)TH * KP1, KP1, TIN, b1, bufI,
      TH);

  lif_scan_f16<<<(TB * TH) / 256, 256, 0, stream>>>(bufI, S1);

  // GEMM2: S1 row-major [8192][1024]: sT=256*1024, sB=1024
  snn_gemm2<<<dim3(TM / 128, TH / 256), 512, 0, stream>>>(
      S1, (long)TB * TH, (long)TH, W2p, (long)TH * TH, TH, b2, bufI, TH);

  lif_scan_f16<<<(TB * TH) / 256, 256, 0, stream>>>(bufI, S2);

  gemm3_kernel<<<(TM * 64) / 256, 256, 0, stream>>>(S2, Wout, bout, buf3);

  scan_out<<<(TB * TOUT + 255) / 256, 256, 0, stream>>>(buf3, (float*)d_out);
}